// Round 14
// baseline (387.292 us; speedup 1.0000x reference)
//
#include <hip/hip_runtime.h>

#define LOG2E 1.4426950408889634f
#define SCALE (2.0f * LOG2E)

__device__ __forceinline__ float fast_exp2(float x) { return __builtin_amdgcn_exp2f(x); }
__device__ __forceinline__ float fast_rcp(float x)  { return __builtin_amdgcn_rcpf(x); }

typedef __attribute__((ext_vector_type(8))) short bf16x8;
typedef __attribute__((ext_vector_type(4))) float f32x4;

// ============ MEASUREMENT ROUND: each kernel loops rep times (idempotent) ============

// ---------------- stage 0: pack (R12 v3) ----------------
__global__ __launch_bounds__(256) void pack_kernel(const float* __restrict__ inputs,
                                                   const float* __restrict__ attn_W,
                                                   ushort* __restrict__ Ap,
                                                   ushort* __restrict__ Bp,
                                                   int rep) {
    __shared__ ushort Hs[64 * 136];
    __shared__ ushort Ls[64 * 136];

    const int bid = blockIdx.x;
    const bool isA = bid < 128;
    const int sub = isA ? bid : bid - 128;
    const int tb = sub >> 2;
    const int kc = sub & 3;
    const int t = threadIdx.x;

    for (int rr = 0; rr < rep; ++rr) {
        __syncthreads();
#pragma unroll
        for (int it = 0; it < 4; ++it) {
            const int u = it * 256 + t;
            const int row = u >> 4;
            const int kc8 = u & 15;
            const float* src;
            if (isA) {
                int sr = ((tb & 3) * 64 + row) * 8 + (tb >> 2);
                src = inputs + (long)sr * 512 + kc * 128 + kc8 * 8;
            } else {
                int r = (tb & 7) * 64 + row;
                src = attn_W + (long)r * 1024 + (tb >> 3) * 512 + kc * 128 + kc8 * 8;
            }
            float4 v0 = *(const float4*)src;
            float4 v1 = *(const float4*)(src + 4);
            float vv[8] = {v0.x, v0.y, v0.z, v0.w, v1.x, v1.y, v1.z, v1.w};
            ushort hi8[8], lo8[8];
#pragma unroll
            for (int j = 0; j < 8; ++j) {
                unsigned u32 = __float_as_uint(vv[j]);
                unsigned h = (u32 + 0x7FFF + ((u32 >> 16) & 1)) >> 16;
                hi8[j] = (ushort)h;
                float lo = vv[j] - __uint_as_float(h << 16);
                unsigned ul = __float_as_uint(lo);
                lo8[j] = (ushort)((ul + 0x7FFF + ((ul >> 16) & 1)) >> 16);
            }
            const int lidx = row * 136 + kc8 * 8;
            *(uint4*)&Hs[lidx] = *(const uint4*)hi8;
            *(uint4*)&Ls[lidx] = *(const uint4*)lo8;
        }
        __syncthreads();

        ushort* P = (isA ? Ap : Bp) + (long)tb * 98304;
#pragma unroll
        for (int it = 0; it < 4; ++it) {
            const int u = it * 256 + t;
            const int l  = u & 63;
            const int fr = (u >> 6) & 3;
            const int ks = (u >> 8) & 1;
            const int ktl = (u >> 9) & 1;
            const int j = fr * 16 + (l & 15);
            const int klocal = ktl * 64 + ks * 32 + (l >> 4) * 8;
            uint4 h  = *(const uint4*)&Hs[j * 136 + klocal];
            uint4 lo = *(const uint4*)&Ls[j * 136 + klocal];
            const int kt0 = kc * 2 + ktl;
            const long off = (long)ks * 2048 + fr * 512 + l * 8;
            if (isA) {
                *(uint4*)(P + (kt0 +  0) * 4096 + off) = h;
                *(uint4*)(P + (kt0 + 16) * 4096 + off) = h;
                *(uint4*)(P + (kt0 +  8) * 4096 + off) = lo;
            } else {
                *(uint4*)(P + (kt0 +  0) * 4096 + off) = h;
                *(uint4*)(P + (kt0 +  8) * 4096 + off) = h;
                *(uint4*)(P + (kt0 + 16) * 4096 + off) = lo;
            }
        }
    }
}

// ---------------- stage 1: MFMA GEMM (R12) ----------------
__global__ __launch_bounds__(512) void mfma_gemm(const ushort* __restrict__ Ap,
                                                 const ushort* __restrict__ Bp,
                                                 const float* __restrict__ attn_b,
                                                 float* __restrict__ E1,
                                                 float* __restrict__ E2,
                                                 int rep) {
    const int xcd = blockIdx.x & 7;
    const int idx = blockIdx.x >> 3;
    const int mb  = xcd * 2 + (idx >> 4);
    const int nb  = idx & 15;
    __shared__ ushort lds[2][12288];

    const int t = threadIdx.x;
    const int lane = t & 63, w = t >> 6;
    const int wr = w >> 1, wc = w & 1;

    const ushort* A0 = Ap + (long)(mb * 2 + 0) * 98304;
    const ushort* A1 = Ap + (long)(mb * 2 + 1) * 98304;
    const ushort* B0 = Bp + (long)nb * 98304;

    for (int rr = 0; rr < rep; ++rr) {
        __syncthreads();
        f32x4 acc[2][2];
#pragma unroll
        for (int i = 0; i < 2; ++i)
#pragma unroll
            for (int j = 0; j < 2; ++j)
                acc[i][j] = (f32x4){0.f, 0.f, 0.f, 0.f};

        uint4 st[3];
#define LOADK(kt)                                                  \
        {                                                          \
            st[0] = ((const uint4*)(A0 + (kt) * 4096))[t];         \
            st[1] = ((const uint4*)(A1 + (kt) * 4096))[t];         \
            st[2] = ((const uint4*)(B0 + (kt) * 4096))[t];         \
        }
#define STOREK(bf)                                                 \
        {                                                          \
            uint4* d = (uint4*)lds[bf];                            \
            d[t] = st[0]; d[t + 512] = st[1]; d[t + 1024] = st[2]; \
        }

        LOADK(0);
        STOREK(0);
        __syncthreads();

        for (int kt = 0; kt < 24; ++kt) {
            if (kt < 23) LOADK(kt + 1);
            const ushort* buf = lds[kt & 1];
#pragma unroll
            for (int ks = 0; ks < 2; ++ks) {
                bf16x8 a[2], b[2];
                const int abase = (wr >> 1) * 4096 + ks * 2048 + (wr & 1) * 1024 + lane * 8;
                const int bbase = 8192 + ks * 2048 + wc * 1024 + lane * 8;
                a[0] = *(const bf16x8*)&buf[abase];
                a[1] = *(const bf16x8*)&buf[abase + 512];
                b[0] = *(const bf16x8*)&buf[bbase];
                b[1] = *(const bf16x8*)&buf[bbase + 512];
#pragma unroll
                for (int mf = 0; mf < 2; ++mf)
#pragma unroll
                    for (int nf = 0; nf < 2; ++nf)
                        acc[mf][nf] = __builtin_amdgcn_mfma_f32_16x16x32_bf16(
                            a[mf], b[nf], acc[mf][nf], 0, 0, 0);
            }
            if (kt < 23) {
                STOREK((kt + 1) & 1);
                __syncthreads();
            }
        }
#undef LOADK
#undef STOREK

#pragma unroll
        for (int nf = 0; nf < 2; ++nf) {
            int n = nb * 64 + wc * 32 + nf * 16 + (lane & 15);
            const bool isE1 = (n < 512);
            float* dst = isE1 ? E1 : E2;
            int o = n & 511;
            float bias = isE1 ? attn_b[o] : 0.0f;
#pragma unroll
            for (int mf = 0; mf < 2; ++mf) {
                int ml = mb * 128 + wr * 32 + mf * 16 + ((lane >> 4) << 2);
                int bb = ml >> 8, l = ml & 255;
                long rowoff = ((long)(bb * 8 + (l >> 5)) * 512 + o) * 32 + (l & 31);
#pragma unroll
                for (int r = 0; r < 4; ++r)
                    dst[rowoff + r] = fast_exp2(SCALE * (acc[mf][nf][r] + bias));
            }
        }
    }
}

// ---------------- stage 2: partial energies (R4-exact) ----------------
__global__ __launch_bounds__(256) void energy_kernel(const float* __restrict__ E1,
                                                     const float* __restrict__ E2,
                                                     const float* __restrict__ sW,
                                                     float* __restrict__ EP,
                                                     int rep) {
    const int bid = blockIdx.x;
    const int s  = bid & 3;
    const int tj = (bid >> 2) & 7;
    const int ti = (bid >> 5) & 7;
    const int b  = bid >> 8;
    __shared__ float p1s[64 * 32];
    __shared__ float p2s[64 * 32];
    __shared__ float csh[128];

    const int t = threadIdx.x;
    const int tx = t & 15, ty = t >> 4;

    if (t < 128) csh[t] = 2.0f * sW[s * 128 + t];

    const float* p1base = E1 + ((long)(b * 8 + ti) * 512 + s * 128) * 32;
    const float* p2base = E2 + ((long)(b * 8 + tj) * 512 + s * 128) * 32;

    for (int rr = 0; rr < rep; ++rr) {
        float acc00 = 0.f, acc01 = 0.f, acc10 = 0.f, acc11 = 0.f;

        for (int c0 = 0; c0 < 128; c0 += 64) {
            __syncthreads();
            const float4* s1 = (const float4*)(p1base + c0 * 32);
            const float4* s2 = (const float4*)(p2base + c0 * 32);
            float4* d1 = (float4*)p1s;
            float4* d2 = (float4*)p2s;
            d1[t] = s1[t];  d1[256 + t] = s1[256 + t];
            d2[t] = s2[t];  d2[256 + t] = s2[256 + t];
            __syncthreads();
#pragma unroll 8
            for (int hh = 0; hh < 64; ++hh) {
                float c = csh[c0 + hh];
                float2 a  = *(const float2*)&p1s[hh * 32 + ty * 2];
                float2 bj = *(const float2*)&p2s[hh * 32 + tx * 2];
                acc00 = fmaf(c, fast_rcp(fmaf(a.x, bj.x, 1.0f)), acc00);
                acc01 = fmaf(c, fast_rcp(fmaf(a.x, bj.y, 1.0f)), acc01);
                acc10 = fmaf(c, fast_rcp(fmaf(a.y, bj.x, 1.0f)), acc10);
                acc11 = fmaf(c, fast_rcp(fmaf(a.y, bj.y, 1.0f)), acc11);
            }
        }

        float* Eb = EP + (long)s * 524288 + (long)b * 65536 + (ti * 32) * 256 + tj * 32;
        *(float2*)&Eb[(ty * 2 + 0) * 256 + tx * 2] = make_float2(acc00, acc01);
        *(float2*)&Eb[(ty * 2 + 1) * 256 + tx * 2] = make_float2(acc10, acc11);
    }
}

// ---------------- stage 3: softmax ----------------
__global__ __launch_bounds__(256) void softmax_kernel(const float* __restrict__ P0,
                                                      const float* __restrict__ P1,
                                                      const float* __restrict__ P2,
                                                      const float* __restrict__ P3,
                                                      float* __restrict__ out,
                                                      int rep) {
    const int b  = blockIdx.x >> 4;
    const int jt = blockIdx.x & 15;
    const int t  = threadIdx.x;
    const int jx = t & 15;
    const int iy = t >> 4;
    const long base = (long)b * 65536 + jt * 16 + jx;

    __shared__ float red[256];

    for (int rr = 0; rr < rep; ++rr) {
        __syncthreads();
        float v[16];
#pragma unroll
        for (int k = 0; k < 16; ++k) {
            long idx = base + (long)(iy + k * 16) * 256;
            v[k] = -(P0[idx] + P1[idx] + P2[idx] + P3[idx]);
        }

        float m = v[0];
#pragma unroll
        for (int k = 1; k < 16; ++k) m = fmaxf(m, v[k]);

        red[t] = m;
        __syncthreads();
        if (t < 128) red[t] = fmaxf(red[t], red[t + 128]);
        __syncthreads();
        if (t < 64) red[t] = fmaxf(red[t], red[t + 64]);
        __syncthreads();
        if (t < 32) red[t] = fmaxf(red[t], red[t + 32]);
        __syncthreads();
        if (t < 16) red[t] = fmaxf(red[t], red[t + 16]);
        __syncthreads();
        m = red[jx];
        __syncthreads();

        float ssum = 0.f;
#pragma unroll
        for (int k = 0; k < 16; ++k) {
            v[k] = fast_exp2((v[k] - m) * LOG2E);
            ssum += v[k];
        }
        red[t] = ssum;
        __syncthreads();
        if (t < 128) red[t] += red[t + 128];
        __syncthreads();
        if (t < 64) red[t] += red[t + 64];
        __syncthreads();
        if (t < 32) red[t] += red[t + 32];
        __syncthreads();
        if (t < 16) red[t] += red[t + 16];
        __syncthreads();
        float inv = fast_rcp(red[jx]);

#pragma unroll
        for (int k = 0; k < 16; ++k) {
            long idx = base + (long)(iy + k * 16) * 256;
            out[idx] = v[k] * inv;
        }
    }
}

extern "C" void kernel_launch(void* const* d_in, const int* in_sizes, int n_in,
                              void* d_out, int out_size, void* d_ws, size_t ws_size,
                              hipStream_t stream) {
    const float* inputs  = (const float*)d_in[0];  // (256, 8, 512)
    const float* attn_W  = (const float*)d_in[1];  // (512, 1024)
    const float* attn_b  = (const float*)d_in[2];  // (512,)
    const float* score_W = (const float*)d_in[3];  // (1, 512)
    float* out = (float*)d_out;                    // (8, 256, 256)

    float* ws = (float*)d_ws;
    float* E1 = ws;
    float* E2 = ws + (1 << 20);
    float* EP = ws + (2 << 20);
    ushort* Ap = (ushort*)(ws + (4 << 20));
    ushort* Bp = Ap + 3145728;

    // MEASUREMENT: reps chosen so each kernel exceeds the ~43us harness fills
    pack_kernel<<<192, 256, 0, stream>>>(inputs, attn_W, Ap, Bp, 24);
    mfma_gemm<<<256, 512, 0, stream>>>(Ap, Bp, attn_b, E1, E2, 12);
    energy_kernel<<<2048, 256, 0, stream>>>(E1, E2, score_W, EP, 6);
    softmax_kernel<<<128, 256, 0, stream>>>(EP, EP + 524288, EP + 2 * 524288,
                                            EP + 3 * 524288, out, 24);
}

// Round 16
// 58.734 us; speedup vs baseline: 6.5940x; 6.5940x over previous
//
#include <hip/hip_runtime.h>

#define LOG2E 1.4426950408889634f
#define SCALE (2.0f * LOG2E)

__device__ __forceinline__ float fast_exp2(float x) { return __builtin_amdgcn_exp2f(x); }
__device__ __forceinline__ float fast_rcp(float x)  { return __builtin_amdgcn_rcpf(x); }

typedef __attribute__((ext_vector_type(8))) short bf16x8;
typedef __attribute__((ext_vector_type(4))) float f32x4;

// ---------------- stage 0: pack A/B into bf16 hi/lo MFMA fragment panels (R12 v3) -------
__global__ __launch_bounds__(256) void pack_kernel(const float* __restrict__ inputs,
                                                   const float* __restrict__ attn_W,
                                                   ushort* __restrict__ Ap,
                                                   ushort* __restrict__ Bp) {
    __shared__ ushort Hs[64 * 136];
    __shared__ ushort Ls[64 * 136];

    const int bid = blockIdx.x;
    const bool isA = bid < 128;
    const int sub = isA ? bid : bid - 128;
    const int tb = sub >> 2;
    const int kc = sub & 3;
    const int t = threadIdx.x;

#pragma unroll
    for (int it = 0; it < 4; ++it) {
        const int u = it * 256 + t;
        const int row = u >> 4;
        const int kc8 = u & 15;
        const float* src;
        if (isA) {
            int sr = ((tb & 3) * 64 + row) * 8 + (tb >> 2);
            src = inputs + (long)sr * 512 + kc * 128 + kc8 * 8;
        } else {
            int r = (tb & 7) * 64 + row;
            src = attn_W + (long)r * 1024 + (tb >> 3) * 512 + kc * 128 + kc8 * 8;
        }
        float4 v0 = *(const float4*)src;
        float4 v1 = *(const float4*)(src + 4);
        float vv[8] = {v0.x, v0.y, v0.z, v0.w, v1.x, v1.y, v1.z, v1.w};
        ushort hi8[8], lo8[8];
#pragma unroll
        for (int j = 0; j < 8; ++j) {
            unsigned u32 = __float_as_uint(vv[j]);
            unsigned h = (u32 + 0x7FFF + ((u32 >> 16) & 1)) >> 16;
            hi8[j] = (ushort)h;
            float lo = vv[j] - __uint_as_float(h << 16);
            unsigned ul = __float_as_uint(lo);
            lo8[j] = (ushort)((ul + 0x7FFF + ((ul >> 16) & 1)) >> 16);
        }
        const int lidx = row * 136 + kc8 * 8;
        *(uint4*)&Hs[lidx] = *(const uint4*)hi8;
        *(uint4*)&Ls[lidx] = *(const uint4*)lo8;
    }
    __syncthreads();

    ushort* P = (isA ? Ap : Bp) + (long)tb * 98304;
#pragma unroll
    for (int it = 0; it < 4; ++it) {
        const int u = it * 256 + t;
        const int l  = u & 63;
        const int fr = (u >> 6) & 3;
        const int ks = (u >> 8) & 1;
        const int ktl = (u >> 9) & 1;
        const int j = fr * 16 + (l & 15);
        const int klocal = ktl * 64 + ks * 32 + (l >> 4) * 8;
        uint4 h  = *(const uint4*)&Hs[j * 136 + klocal];
        uint4 lo = *(const uint4*)&Ls[j * 136 + klocal];
        const int kt0 = kc * 2 + ktl;
        const long off = (long)ks * 2048 + fr * 512 + l * 8;
        if (isA) {
            *(uint4*)(P + (kt0 +  0) * 4096 + off) = h;
            *(uint4*)(P + (kt0 + 16) * 4096 + off) = h;
            *(uint4*)(P + (kt0 +  8) * 4096 + off) = lo;
        } else {
            *(uint4*)(P + (kt0 +  0) * 4096 + off) = h;
            *(uint4*)(P + (kt0 +  8) * 4096 + off) = h;
            *(uint4*)(P + (kt0 + 16) * 4096 + off) = lo;
        }
    }
}

// ---------------- stage 1: MFMA GEMM (R12, 128x64 tile, 8 waves 32x32) ----------------
__global__ __launch_bounds__(512) void mfma_gemm(const ushort* __restrict__ Ap,
                                                 const ushort* __restrict__ Bp,
                                                 const float* __restrict__ attn_b,
                                                 float* __restrict__ E1,
                                                 float* __restrict__ E2) {
    const int xcd = blockIdx.x & 7;
    const int idx = blockIdx.x >> 3;
    const int mb  = xcd * 2 + (idx >> 4);
    const int nb  = idx & 15;
    __shared__ ushort lds[2][12288];

    const int t = threadIdx.x;
    const int lane = t & 63, w = t >> 6;
    const int wr = w >> 1, wc = w & 1;

    const ushort* A0 = Ap + (long)(mb * 2 + 0) * 98304;
    const ushort* A1 = Ap + (long)(mb * 2 + 1) * 98304;
    const ushort* B0 = Bp + (long)nb * 98304;

    f32x4 acc[2][2];
#pragma unroll
    for (int i = 0; i < 2; ++i)
#pragma unroll
        for (int j = 0; j < 2; ++j)
            acc[i][j] = (f32x4){0.f, 0.f, 0.f, 0.f};

    uint4 st[3];
#define LOADK(kt)                                                  \
    {                                                              \
        st[0] = ((const uint4*)(A0 + (kt) * 4096))[t];             \
        st[1] = ((const uint4*)(A1 + (kt) * 4096))[t];             \
        st[2] = ((const uint4*)(B0 + (kt) * 4096))[t];             \
    }
#define STOREK(bf)                                                 \
    {                                                              \
        uint4* d = (uint4*)lds[bf];                                \
        d[t] = st[0]; d[t + 512] = st[1]; d[t + 1024] = st[2];     \
    }

    LOADK(0);
    STOREK(0);
    __syncthreads();

    for (int kt = 0; kt < 24; ++kt) {
        if (kt < 23) LOADK(kt + 1);
        const ushort* buf = lds[kt & 1];
#pragma unroll
        for (int ks = 0; ks < 2; ++ks) {
            bf16x8 a[2], b[2];
            const int abase = (wr >> 1) * 4096 + ks * 2048 + (wr & 1) * 1024 + lane * 8;
            const int bbase = 8192 + ks * 2048 + wc * 1024 + lane * 8;
            a[0] = *(const bf16x8*)&buf[abase];
            a[1] = *(const bf16x8*)&buf[abase + 512];
            b[0] = *(const bf16x8*)&buf[bbase];
            b[1] = *(const bf16x8*)&buf[bbase + 512];
#pragma unroll
            for (int mf = 0; mf < 2; ++mf)
#pragma unroll
                for (int nf = 0; nf < 2; ++nf)
                    acc[mf][nf] = __builtin_amdgcn_mfma_f32_16x16x32_bf16(
                        a[mf], b[nf], acc[mf][nf], 0, 0, 0);
        }
        if (kt < 23) {
            STOREK((kt + 1) & 1);
            __syncthreads();
        }
    }
#undef LOADK
#undef STOREK

#pragma unroll
    for (int nf = 0; nf < 2; ++nf) {
        int n = nb * 64 + wc * 32 + nf * 16 + (lane & 15);
        const bool isE1 = (n < 512);
        float* dst = isE1 ? E1 : E2;
        int o = n & 511;
        float bias = isE1 ? attn_b[o] : 0.0f;
#pragma unroll
        for (int mf = 0; mf < 2; ++mf) {
            int ml = mb * 128 + wr * 32 + mf * 16 + ((lane >> 4) << 2);
            int bb = ml >> 8, l = ml & 255;
            long rowoff = ((long)(bb * 8 + (l >> 5)) * 512 + o) * 32 + (l & 31);
#pragma unroll
            for (int r = 0; r < 4; ++r)
                dst[rowoff + r] = fast_exp2(SCALE * (acc[mf][nf][r] + bias));
        }
    }
}

// ---------------- stage 2: partial energies v2 ----------------
// EP[s][b][i][j] = sum_{o in chunk s (128)} c_o * rcp(1 + E1[b,i,o]*E2[b,j,o])
// 64i x 32j tile, 4x2/thread, [hh][i] LDS, 2-way exact o-pair combine:
//   c0/ya + c1/yb = (c0*yb + c1*ya) * rcp(ya*yb)   (ya,yb > 1, no cancellation)
__global__ __launch_bounds__(256) void energy_kernel(const float* __restrict__ E1,
                                                     const float* __restrict__ E2,
                                                     const float* __restrict__ sW,
                                                     float* __restrict__ EP) {
    const int bid = blockIdx.x;       // 1024 = 8b * 4ti * 8tj * 4s
    const int s  = bid & 3;
    const int tj = (bid >> 2) & 7;
    const int ti = (bid >> 5) & 3;
    const int b  = bid >> 7;
    __shared__ float As[64 * 64];     // [hh][i 0..63]
    __shared__ float Bs[64 * 32];     // [hh][j 0..31]
    __shared__ float csh[128];

    const int t = threadIdx.x;
    const int tx = t & 15, ty = t >> 4;

    if (t < 128) csh[t] = 2.0f * sW[s * 128 + t];

    const float* e1base = E1 + ((long)(b * 8 + ti * 2) * 512 + s * 128) * 32; // 2 panel rows
    const float* e2base = E2 + ((long)(b * 8 + tj) * 512 + s * 128) * 32;     // 1 panel row

    float acc[4][2];
#pragma unroll
    for (int i = 0; i < 4; ++i) { acc[i][0] = 0.f; acc[i][1] = 0.f; }

    for (int c0 = 0; c0 < 128; c0 += 64) {
        __syncthreads();
        // stage As: 1024 float4s; f -> o_local = f>>4, i = (f&15)*4
        {
            const float4* s1 = (const float4*)(e1base + (long)c0 * 32);
            // E1 element (half, o, ii) at f32 index half*16384 + o*32 + ii
#pragma unroll
            for (int it = 0; it < 4; ++it) {
                int f = it * 256 + t;
                int ol = f >> 4;
                int i4 = (f & 15) * 4;
                int half = i4 >> 5, ii = i4 & 31;
                float4 v = s1[(half * 16384 + ol * 32 + ii) >> 2];
                *(float4*)&As[ol * 64 + i4] = v;
            }
            const float4* s2 = (const float4*)(e2base + (long)c0 * 32);
#pragma unroll
            for (int it = 0; it < 2; ++it) {
                int f = it * 256 + t;
                int ol = f >> 3;
                int j4 = (f & 7) * 4;
                float4 v = s2[(ol * 32 + j4) >> 2];
                *(float4*)&Bs[ol * 32 + j4] = v;
            }
        }
        __syncthreads();

#pragma unroll 4
        for (int p = 0; p < 32; ++p) {
            const float c0v = csh[c0 + 2 * p];
            const float c1v = csh[c0 + 2 * p + 1];
            float4 a0 = *(const float4*)&As[(2 * p) * 64 + ty * 4];
            float4 a1 = *(const float4*)&As[(2 * p + 1) * 64 + ty * 4];
            float2 b0 = *(const float2*)&Bs[(2 * p) * 32 + tx * 2];
            float2 b1 = *(const float2*)&Bs[(2 * p + 1) * 32 + tx * 2];
            const float a0v[4] = {a0.x, a0.y, a0.z, a0.w};
            const float a1v[4] = {a1.x, a1.y, a1.z, a1.w};
            const float b0v[2] = {b0.x, b0.y};
            const float b1v[2] = {b1.x, b1.y};
#pragma unroll
            for (int i = 0; i < 4; ++i) {
#pragma unroll
                for (int j = 0; j < 2; ++j) {
                    float ya = fmaf(a0v[i], b0v[j], 1.0f);
                    float yb = fmaf(a1v[i], b1v[j], 1.0f);
                    float num = fmaf(c0v, yb, c1v * ya);
                    float den = ya * yb;
                    acc[i][j] = fmaf(num, fast_rcp(den), acc[i][j]);
                }
            }
        }
    }

    float* Eb = EP + (long)s * 524288 + (long)b * 65536 +
                (long)(ti * 64 + ty * 4) * 256 + tj * 32 + tx * 2;
#pragma unroll
    for (int i = 0; i < 4; ++i)
        *(float2*)&Eb[i * 256] = make_float2(acc[i][0], acc[i][1]);
}

// ---------------- stage 3: combine partials + softmax over i (axis=1) ----------------
__global__ __launch_bounds__(256) void softmax_kernel(const float* __restrict__ P0,
                                                      const float* __restrict__ P1,
                                                      const float* __restrict__ P2,
                                                      const float* __restrict__ P3,
                                                      float* __restrict__ out) {
    const int b  = blockIdx.x >> 4;
    const int jt = blockIdx.x & 15;
    const int t  = threadIdx.x;
    const int jx = t & 15;
    const int iy = t >> 4;
    const long base = (long)b * 65536 + jt * 16 + jx;

    float v[16];
#pragma unroll
    for (int k = 0; k < 16; ++k) {
        long idx = base + (long)(iy + k * 16) * 256;
        v[k] = -(P0[idx] + P1[idx] + P2[idx] + P3[idx]);
    }

    float m = v[0];
#pragma unroll
    for (int k = 1; k < 16; ++k) m = fmaxf(m, v[k]);

    __shared__ float red[256];
    red[t] = m;
    __syncthreads();
    if (t < 128) red[t] = fmaxf(red[t], red[t + 128]);
    __syncthreads();
    if (t < 64) red[t] = fmaxf(red[t], red[t + 64]);
    __syncthreads();
    if (t < 32) red[t] = fmaxf(red[t], red[t + 32]);
    __syncthreads();
    if (t < 16) red[t] = fmaxf(red[t], red[t + 16]);
    __syncthreads();
    m = red[jx];
    __syncthreads();

    float ssum = 0.f;
#pragma unroll
    for (int k = 0; k < 16; ++k) {
        v[k] = fast_exp2((v[k] - m) * LOG2E);
        ssum += v[k];
    }
    red[t] = ssum;
    __syncthreads();
    if (t < 128) red[t] += red[t + 128];
    __syncthreads();
    if (t < 64) red[t] += red[t + 64];
    __syncthreads();
    if (t < 32) red[t] += red[t + 32];
    __syncthreads();
    if (t < 16) red[t] += red[t + 16];
    __syncthreads();
    float inv = fast_rcp(red[jx]);

#pragma unroll
    for (int k = 0; k < 16; ++k) {
        long idx = base + (long)(iy + k * 16) * 256;
        out[idx] = v[k] * inv;
    }
}

extern "C" void kernel_launch(void* const* d_in, const int* in_sizes, int n_in,
                              void* d_out, int out_size, void* d_ws, size_t ws_size,
                              hipStream_t stream) {
    const float* inputs  = (const float*)d_in[0];  // (256, 8, 512)
    const float* attn_W  = (const float*)d_in[1];  // (512, 1024)
    const float* attn_b  = (const float*)d_in[2];  // (512,)
    const float* score_W = (const float*)d_in[3];  // (1, 512)
    float* out = (float*)d_out;                    // (8, 256, 256)

    float* ws = (float*)d_ws;
    float* E1 = ws;                                // 1M f32 exp panel
    float* E2 = ws + (1 << 20);                    // 1M f32
    float* EP = ws + (2 << 20);                    // 4 * 512K f32 partials (8 MB)
    ushort* Ap = (ushort*)(ws + (4 << 20));        // 3.146M bf16
    ushort* Bp = Ap + 3145728;                     // 1.573M bf16

    pack_kernel<<<192, 256, 0, stream>>>(inputs, attn_W, Ap, Bp);
    mfma_gemm<<<256, 512, 0, stream>>>(Ap, Bp, attn_b, E1, E2);
    energy_kernel<<<1024, 256, 0, stream>>>(E1, E2, score_W, EP);
    softmax_kernel<<<128, 256, 0, stream>>>(EP, EP + 524288, EP + 2 * 524288,
                                            EP + 3 * 524288, out);
}

// Round 17
// 57.398 us; speedup vs baseline: 6.7475x; 1.0233x over previous
//
#include <hip/hip_runtime.h>

#define LOG2E 1.4426950408889634f
#define SCALE (2.0f * LOG2E)

__device__ __forceinline__ float fast_exp2(float x) { return __builtin_amdgcn_exp2f(x); }
__device__ __forceinline__ float fast_rcp(float x)  { return __builtin_amdgcn_rcpf(x); }

typedef __attribute__((ext_vector_type(8))) short bf16x8;
typedef __attribute__((ext_vector_type(4))) float f32x4;

// ---------------- stage 0: pack A/B into bf16 hi/lo MFMA fragment panels (R12 v3) -------
__global__ __launch_bounds__(256) void pack_kernel(const float* __restrict__ inputs,
                                                   const float* __restrict__ attn_W,
                                                   ushort* __restrict__ Ap,
                                                   ushort* __restrict__ Bp) {
    __shared__ ushort Hs[64 * 136];
    __shared__ ushort Ls[64 * 136];

    const int bid = blockIdx.x;
    const bool isA = bid < 128;
    const int sub = isA ? bid : bid - 128;
    const int tb = sub >> 2;
    const int kc = sub & 3;
    const int t = threadIdx.x;

#pragma unroll
    for (int it = 0; it < 4; ++it) {
        const int u = it * 256 + t;
        const int row = u >> 4;
        const int kc8 = u & 15;
        const float* src;
        if (isA) {
            int sr = ((tb & 3) * 64 + row) * 8 + (tb >> 2);
            src = inputs + (long)sr * 512 + kc * 128 + kc8 * 8;
        } else {
            int r = (tb & 7) * 64 + row;
            src = attn_W + (long)r * 1024 + (tb >> 3) * 512 + kc * 128 + kc8 * 8;
        }
        float4 v0 = *(const float4*)src;
        float4 v1 = *(const float4*)(src + 4);
        float vv[8] = {v0.x, v0.y, v0.z, v0.w, v1.x, v1.y, v1.z, v1.w};
        ushort hi8[8], lo8[8];
#pragma unroll
        for (int j = 0; j < 8; ++j) {
            unsigned u32 = __float_as_uint(vv[j]);
            unsigned h = (u32 + 0x7FFF + ((u32 >> 16) & 1)) >> 16;
            hi8[j] = (ushort)h;
            float lo = vv[j] - __uint_as_float(h << 16);
            unsigned ul = __float_as_uint(lo);
            lo8[j] = (ushort)((ul + 0x7FFF + ((ul >> 16) & 1)) >> 16);
        }
        const int lidx = row * 136 + kc8 * 8;
        *(uint4*)&Hs[lidx] = *(const uint4*)hi8;
        *(uint4*)&Ls[lidx] = *(const uint4*)lo8;
    }
    __syncthreads();

    ushort* P = (isA ? Ap : Bp) + (long)tb * 98304;
#pragma unroll
    for (int it = 0; it < 4; ++it) {
        const int u = it * 256 + t;
        const int l  = u & 63;
        const int fr = (u >> 6) & 3;
        const int ks = (u >> 8) & 1;
        const int ktl = (u >> 9) & 1;
        const int j = fr * 16 + (l & 15);
        const int klocal = ktl * 64 + ks * 32 + (l >> 4) * 8;
        uint4 h  = *(const uint4*)&Hs[j * 136 + klocal];
        uint4 lo = *(const uint4*)&Ls[j * 136 + klocal];
        const int kt0 = kc * 2 + ktl;
        const long off = (long)ks * 2048 + fr * 512 + l * 8;
        if (isA) {
            *(uint4*)(P + (kt0 +  0) * 4096 + off) = h;
            *(uint4*)(P + (kt0 + 16) * 4096 + off) = h;
            *(uint4*)(P + (kt0 +  8) * 4096 + off) = lo;
        } else {
            *(uint4*)(P + (kt0 +  0) * 4096 + off) = h;
            *(uint4*)(P + (kt0 +  8) * 4096 + off) = h;
            *(uint4*)(P + (kt0 + 16) * 4096 + off) = lo;
        }
    }
}

// ---------------- stage 1: MFMA GEMM (R12, 128x64 tile, 8 waves 32x32) ----------------
__global__ __launch_bounds__(512) void mfma_gemm(const ushort* __restrict__ Ap,
                                                 const ushort* __restrict__ Bp,
                                                 const float* __restrict__ attn_b,
                                                 float* __restrict__ E1,
                                                 float* __restrict__ E2) {
    const int xcd = blockIdx.x & 7;
    const int idx = blockIdx.x >> 3;
    const int mb  = xcd * 2 + (idx >> 4);
    const int nb  = idx & 15;
    __shared__ ushort lds[2][12288];

    const int t = threadIdx.x;
    const int lane = t & 63, w = t >> 6;
    const int wr = w >> 1, wc = w & 1;

    const ushort* A0 = Ap + (long)(mb * 2 + 0) * 98304;
    const ushort* A1 = Ap + (long)(mb * 2 + 1) * 98304;
    const ushort* B0 = Bp + (long)nb * 98304;

    f32x4 acc[2][2];
#pragma unroll
    for (int i = 0; i < 2; ++i)
#pragma unroll
        for (int j = 0; j < 2; ++j)
            acc[i][j] = (f32x4){0.f, 0.f, 0.f, 0.f};

    uint4 st[3];
#define LOADK(kt)                                                  \
    {                                                              \
        st[0] = ((const uint4*)(A0 + (kt) * 4096))[t];             \
        st[1] = ((const uint4*)(A1 + (kt) * 4096))[t];             \
        st[2] = ((const uint4*)(B0 + (kt) * 4096))[t];             \
    }
#define STOREK(bf)                                                 \
    {                                                              \
        uint4* d = (uint4*)lds[bf];                                \
        d[t] = st[0]; d[t + 512] = st[1]; d[t + 1024] = st[2];     \
    }

    LOADK(0);
    STOREK(0);
    __syncthreads();

    for (int kt = 0; kt < 24; ++kt) {
        if (kt < 23) LOADK(kt + 1);
        const ushort* buf = lds[kt & 1];
#pragma unroll
        for (int ks = 0; ks < 2; ++ks) {
            bf16x8 a[2], b[2];
            const int abase = (wr >> 1) * 4096 + ks * 2048 + (wr & 1) * 1024 + lane * 8;
            const int bbase = 8192 + ks * 2048 + wc * 1024 + lane * 8;
            a[0] = *(const bf16x8*)&buf[abase];
            a[1] = *(const bf16x8*)&buf[abase + 512];
            b[0] = *(const bf16x8*)&buf[bbase];
            b[1] = *(const bf16x8*)&buf[bbase + 512];
#pragma unroll
            for (int mf = 0; mf < 2; ++mf)
#pragma unroll
                for (int nf = 0; nf < 2; ++nf)
                    acc[mf][nf] = __builtin_amdgcn_mfma_f32_16x16x32_bf16(
                        a[mf], b[nf], acc[mf][nf], 0, 0, 0);
        }
        if (kt < 23) {
            STOREK((kt + 1) & 1);
            __syncthreads();
        }
    }
#undef LOADK
#undef STOREK

#pragma unroll
    for (int nf = 0; nf < 2; ++nf) {
        int n = nb * 64 + wc * 32 + nf * 16 + (lane & 15);
        const bool isE1 = (n < 512);
        float* dst = isE1 ? E1 : E2;
        int o = n & 511;
        float bias = isE1 ? attn_b[o] : 0.0f;
#pragma unroll
        for (int mf = 0; mf < 2; ++mf) {
            int ml = mb * 128 + wr * 32 + mf * 16 + ((lane >> 4) << 2);
            int bb = ml >> 8, l = ml & 255;
            long rowoff = ((long)(bb * 8 + (l >> 5)) * 512 + o) * 32 + (l & 31);
#pragma unroll
            for (int r = 0; r < 4; ++r)
                dst[rowoff + r] = fast_exp2(SCALE * (acc[mf][nf][r] + bias));
        }
    }
}

// ---------------- stage 2: partial energies v4 ----------------
// EP[s][b][i][j] = sum_{o in chunk s (128)} c_o * rcp(1 + E1[b,i,o]*E2[b,j,o])
// 64i x 64j tile, 4x4/thread, [o][i] LDS (32-o chunks), 4-way exact rcp combine:
//   sum c_q/y_q = n/d, d = y0y1y2y3, n = (c0y1+c1y0)y23 + (c2y3+c3y2)y01   (y>1 always)
__global__ __launch_bounds__(256) void energy_kernel(const float* __restrict__ E1,
                                                     const float* __restrict__ E2,
                                                     const float* __restrict__ sW,
                                                     float* __restrict__ EP) {
    const int bid = blockIdx.x;       // 512 = s(4) b(8) ti(4) tj(4)
    const int tj = bid & 3;
    const int ti = (bid >> 2) & 3;
    const int b  = (bid >> 4) & 7;
    const int s  = bid >> 7;
    __shared__ float As[32 * 64];     // [o_local][i 0..63]
    __shared__ float Bs[32 * 64];     // [o_local][j 0..63]
    __shared__ float csh[128];

    const int t = threadIdx.x;
    const int tx = t & 15, ty = t >> 4;

    if (t < 128) csh[t] = 2.0f * sW[s * 128 + t];

    const float* e1base = E1 + (long)(b * 8 + ti * 2) * 16384;   // 2 panel rows (64 i)
    const float* e2base = E2 + (long)(b * 8 + tj * 2) * 16384;   // 2 panel rows (64 j)

    float acc[4][4];
#pragma unroll
    for (int i = 0; i < 4; ++i)
#pragma unroll
        for (int j = 0; j < 4; ++j) acc[i][j] = 0.f;

    for (int c0 = 0; c0 < 128; c0 += 32) {
        __syncthreads();
        // stage 32-o chunk: 512 float4 per buffer, 2 per thread
#pragma unroll
        for (int it = 0; it < 2; ++it) {
            const int f = it * 256 + t;
            const int ol = f >> 4;                 // 0..31
            const int i4 = (f & 15) * 4;           // 0..60
            const long srcoff = (long)(i4 >> 5) * 16384 + (long)(s * 128 + c0 + ol) * 32 + (i4 & 31);
            *(float4*)&As[ol * 64 + i4] = *(const float4*)(e1base + srcoff);
            *(float4*)&Bs[ol * 64 + i4] = *(const float4*)(e2base + srcoff);
        }
        __syncthreads();

#pragma unroll 2
        for (int p = 0; p < 8; ++p) {            // 8 o-quads per chunk
            const float4 c4 = *(const float4*)&csh[c0 + p * 4];
            float4 a0 = *(const float4*)&As[(p * 4 + 0) * 64 + ty * 4];
            float4 a1 = *(const float4*)&As[(p * 4 + 1) * 64 + ty * 4];
            float4 a2 = *(const float4*)&As[(p * 4 + 2) * 64 + ty * 4];
            float4 a3 = *(const float4*)&As[(p * 4 + 3) * 64 + ty * 4];
            float4 b0 = *(const float4*)&Bs[(p * 4 + 0) * 64 + tx * 4];
            float4 b1 = *(const float4*)&Bs[(p * 4 + 1) * 64 + tx * 4];
            float4 b2 = *(const float4*)&Bs[(p * 4 + 2) * 64 + tx * 4];
            float4 b3 = *(const float4*)&Bs[(p * 4 + 3) * 64 + tx * 4];
            const float a0v[4] = {a0.x, a0.y, a0.z, a0.w};
            const float a1v[4] = {a1.x, a1.y, a1.z, a1.w};
            const float a2v[4] = {a2.x, a2.y, a2.z, a2.w};
            const float a3v[4] = {a3.x, a3.y, a3.z, a3.w};
            const float b0v[4] = {b0.x, b0.y, b0.z, b0.w};
            const float b1v[4] = {b1.x, b1.y, b1.z, b1.w};
            const float b2v[4] = {b2.x, b2.y, b2.z, b2.w};
            const float b3v[4] = {b3.x, b3.y, b3.z, b3.w};
#pragma unroll
            for (int i = 0; i < 4; ++i) {
#pragma unroll
                for (int j = 0; j < 4; ++j) {
                    float y0 = fmaf(a0v[i], b0v[j], 1.0f);
                    float y1 = fmaf(a1v[i], b1v[j], 1.0f);
                    float y2 = fmaf(a2v[i], b2v[j], 1.0f);
                    float y3 = fmaf(a3v[i], b3v[j], 1.0f);
                    float y01 = y0 * y1, y23 = y2 * y3;
                    float d = y01 * y23;
                    float n01 = fmaf(c4.x, y1, c4.y * y0);
                    float n23 = fmaf(c4.z, y3, c4.w * y2);
                    float n = fmaf(n01, y23, n23 * y01);
                    acc[i][j] = fmaf(n, fast_rcp(d), acc[i][j]);
                }
            }
        }
    }

    float* Eb = EP + (long)s * 524288 + (long)b * 65536 +
                (long)(ti * 64 + ty * 4) * 256 + tj * 64 + tx * 4;
#pragma unroll
    for (int i = 0; i < 4; ++i)
        *(float4*)&Eb[i * 256] = make_float4(acc[i][0], acc[i][1], acc[i][2], acc[i][3]);
}

// ---------------- stage 3: combine partials + softmax over i (axis=1) ----------------
__global__ __launch_bounds__(256) void softmax_kernel(const float* __restrict__ P0,
                                                      const float* __restrict__ P1,
                                                      const float* __restrict__ P2,
                                                      const float* __restrict__ P3,
                                                      float* __restrict__ out) {
    const int b  = blockIdx.x >> 4;
    const int jt = blockIdx.x & 15;
    const int t  = threadIdx.x;
    const int jx = t & 15;
    const int iy = t >> 4;
    const long base = (long)b * 65536 + jt * 16 + jx;

    float v[16];
#pragma unroll
    for (int k = 0; k < 16; ++k) {
        long idx = base + (long)(iy + k * 16) * 256;
        v[k] = -(P0[idx] + P1[idx] + P2[idx] + P3[idx]);
    }

    float m = v[0];
#pragma unroll
    for (int k = 1; k < 16; ++k) m = fmaxf(m, v[k]);

    __shared__ float red[256];
    red[t] = m;
    __syncthreads();
    if (t < 128) red[t] = fmaxf(red[t], red[t + 128]);
    __syncthreads();
    if (t < 64) red[t] = fmaxf(red[t], red[t + 64]);
    __syncthreads();
    if (t < 32) red[t] = fmaxf(red[t], red[t + 32]);
    __syncthreads();
    if (t < 16) red[t] = fmaxf(red[t], red[t + 16]);
    __syncthreads();
    m = red[jx];
    __syncthreads();

    float ssum = 0.f;
#pragma unroll
    for (int k = 0; k < 16; ++k) {
        v[k] = fast_exp2((v[k] - m) * LOG2E);
        ssum += v[k];
    }
    red[t] = ssum;
    __syncthreads();
    if (t < 128) red[t] += red[t + 128];
    __syncthreads();
    if (t < 64) red[t] += red[t + 64];
    __syncthreads();
    if (t < 32) red[t] += red[t + 32];
    __syncthreads();
    if (t < 16) red[t] += red[t + 16];
    __syncthreads();
    float inv = fast_rcp(red[jx]);

#pragma unroll
    for (int k = 0; k < 16; ++k) {
        long idx = base + (long)(iy + k * 16) * 256;
        out[idx] = v[k] * inv;
    }
}

extern "C" void kernel_launch(void* const* d_in, const int* in_sizes, int n_in,
                              void* d_out, int out_size, void* d_ws, size_t ws_size,
                              hipStream_t stream) {
    const float* inputs  = (const float*)d_in[0];  // (256, 8, 512)
    const float* attn_W  = (const float*)d_in[1];  // (512, 1024)
    const float* attn_b  = (const float*)d_in[2];  // (512,)
    const float* score_W = (const float*)d_in[3];  // (1, 512)
    float* out = (float*)d_out;                    // (8, 256, 256)

    float* ws = (float*)d_ws;
    float* E1 = ws;                                // 1M f32 exp panel
    float* E2 = ws + (1 << 20);                    // 1M f32
    float* EP = ws + (2 << 20);                    // 4 * 512K f32 partials (8 MB)
    ushort* Ap = (ushort*)(ws + (4 << 20));        // 3.146M bf16
    ushort* Bp = Ap + 3145728;                     // 1.573M bf16

    pack_kernel<<<192, 256, 0, stream>>>(inputs, attn_W, Ap, Bp);
    mfma_gemm<<<256, 512, 0, stream>>>(Ap, Bp, attn_b, E1, E2);
    energy_kernel<<<512, 256, 0, stream>>>(E1, E2, score_W, EP);
    softmax_kernel<<<128, 256, 0, stream>>>(EP, EP + 524288, EP + 2 * 524288,
                                            EP + 3 * 524288, out);
}

// Round 20
// 53.418 us; speedup vs baseline: 7.2502x; 1.0745x over previous
//
#include <hip/hip_runtime.h>

#define LOG2E 1.4426950408889634f
#define SCALE (2.0f * LOG2E)

__device__ __forceinline__ float fast_exp2(float x) { return __builtin_amdgcn_exp2f(x); }
__device__ __forceinline__ float fast_rcp(float x)  { return __builtin_amdgcn_rcpf(x); }

typedef __attribute__((ext_vector_type(8))) short bf16x8;
typedef __attribute__((ext_vector_type(4))) float f32x4;

__device__ __forceinline__ void cvt_hilo8(const float* vv, ushort* hi8, ushort* lo8) {
#pragma unroll
    for (int j = 0; j < 8; ++j) {
        unsigned u32 = __float_as_uint(vv[j]);
        unsigned h = (u32 + 0x7FFF + ((u32 >> 16) & 1)) >> 16;   // RN bf16
        hi8[j] = (ushort)h;
        float lo = vv[j] - __uint_as_float(h << 16);
        unsigned ul = __float_as_uint(lo);
        lo8[j] = (ushort)((ul + 0x7FFF + ((ul >> 16) & 1)) >> 16);
    }
}

// ---------------- stage 0+1 fused: MFMA GEMM direct from f32 (hi/lo on the fly) --------
// Logical: C[m,n] = x_hi*w_hi + x_lo*w_hi + x_hi*w_lo summed over k=0..511 (lo*lo dropped).
// 256 blocks x 512 threads, tile 128m x 64n, 8 waves (4m x 2n, 32x32 each).
// 8 source-chunks of 64 k; per chunk: stage f32 -> Ahi/Alo/Bhi/Blo LDS fragments,
// then 3 passes (Ahi*Bhi, Alo*Bhi, Ahi*Blo). 192 MFMA/wave total (same as packed version).
// Epilogue stores exp panels E1/E2 (layout unchanged).
__global__ __launch_bounds__(512) void mfma_gemm(const float* __restrict__ inputs,
                                                 const float* __restrict__ attn_W,
                                                 const float* __restrict__ attn_b,
                                                 float* __restrict__ E1,
                                                 float* __restrict__ E2) {
    const int xcd = blockIdx.x & 7;
    const int idx = blockIdx.x >> 3;
    const int mb  = xcd * 2 + (idx >> 4);  // 0..15
    const int nb  = idx & 15;              // 0..15
    // LDS: Ahi[8192] | Alo[8192] | Bhi[4096] | Blo[4096]  (ushort) = 48KB
    __shared__ ushort lds[24576];
    ushort* const Ahi = lds;
    ushort* const Alo = lds + 8192;
    ushort* const Bhi = lds + 16384;
    ushort* const Blo = lds + 20480;

    const int t = threadIdx.x;             // 0..511
    const int lane = t & 63, w = t >> 6;
    const int wr = w >> 1, wc = w & 1;     // wave tile 32(m) x 32(n)

    // staging unit geometry (fragment mapping verified: m=fr*16+(lane&15), k=ks*32+(lane>>4)*8+j)
    // A: units u = t, t+512 : row = u>>3 (0..127), k8 = u&7
    // B: unit  u = t        : nloc = u>>3 (0..63), k8 = u&7
    const int arow0 = t >> 3, ak8 = t & 7;          // A unit 0
    const int arow1 = (t + 512) >> 3;               // A unit 1 (same k8)
    const int m0 = mb * 128 + arow0;
    const int m1 = mb * 128 + arow1;
    const float* asrc0 = inputs + (long)((m0 & 255) * 8 + (m0 >> 8)) * 512 + ak8 * 8;
    const float* asrc1 = inputs + (long)((m1 & 255) * 8 + (m1 >> 8)) * 512 + ak8 * 8;
    const int nloc = t >> 3, bk8 = t & 7;
    const int ngl = nb * 64 + nloc;
    const float* bsrc = attn_W + (long)(ngl & 511) * 1024 + (ngl >> 9) * 512 + bk8 * 8;

    // LDS write offsets (ushort units)
    const int aoff0 = (arow0 >> 6) * 4096 + (ak8 >> 2) * 2048 + ((arow0 & 63) >> 4) * 512 +
                      ((ak8 & 3) * 16 + (arow0 & 15)) * 8;
    const int aoff1 = (arow1 >> 6) * 4096 + (ak8 >> 2) * 2048 + ((arow1 & 63) >> 4) * 512 +
                      ((ak8 & 3) * 16 + (arow1 & 15)) * 8;
    const int boff  = (bk8 >> 2) * 2048 + (nloc >> 4) * 512 +
                      ((bk8 & 3) * 16 + (nloc & 15)) * 8;

    f32x4 acc[2][2];
#pragma unroll
    for (int i = 0; i < 2; ++i)
#pragma unroll
        for (int j = 0; j < 2; ++j)
            acc[i][j] = (f32x4){0.f, 0.f, 0.f, 0.f};

    float ra0[8], ra1[8], rb[8];
#define LOADF(ss)                                                              \
    {                                                                          \
        *(float4*)&ra0[0] = *(const float4*)(asrc0 + (ss) * 64);               \
        *(float4*)&ra0[4] = *(const float4*)(asrc0 + (ss) * 64 + 4);           \
        *(float4*)&ra1[0] = *(const float4*)(asrc1 + (ss) * 64);               \
        *(float4*)&ra1[4] = *(const float4*)(asrc1 + (ss) * 64 + 4);           \
        *(float4*)&rb[0]  = *(const float4*)(bsrc  + (ss) * 64);               \
        *(float4*)&rb[4]  = *(const float4*)(bsrc  + (ss) * 64 + 4);           \
    }

    LOADF(0);

    for (int ss = 0; ss < 8; ++ss) {
        __syncthreads();   // previous compute done; safe to overwrite LDS
        {
            ushort h8[8], l8[8];
            cvt_hilo8(ra0, h8, l8);
            *(uint4*)&Ahi[aoff0] = *(const uint4*)h8;
            *(uint4*)&Alo[aoff0] = *(const uint4*)l8;
            cvt_hilo8(ra1, h8, l8);
            *(uint4*)&Ahi[aoff1] = *(const uint4*)h8;
            *(uint4*)&Alo[aoff1] = *(const uint4*)l8;
            cvt_hilo8(rb, h8, l8);
            *(uint4*)&Bhi[boff] = *(const uint4*)h8;
            *(uint4*)&Blo[boff] = *(const uint4*)l8;
        }
        if (ss < 7) LOADF(ss + 1);   // drains under the compute below
        __syncthreads();

        // 3 passes: (Ahi,Bhi), (Alo,Bhi), (Ahi,Blo)
#pragma unroll
        for (int pass = 0; pass < 3; ++pass) {
            const ushort* Ab = (pass == 1) ? Alo : Ahi;
            const ushort* Bb = (pass == 2) ? Blo : Bhi;
#pragma unroll
            for (int ks = 0; ks < 2; ++ks) {
                bf16x8 a[2], b[2];
                const int abase = (wr >> 1) * 4096 + ks * 2048 + (wr & 1) * 1024 + lane * 8;
                const int bbase = ks * 2048 + wc * 1024 + lane * 8;
                a[0] = *(const bf16x8*)&Ab[abase];
                a[1] = *(const bf16x8*)&Ab[abase + 512];
                b[0] = *(const bf16x8*)&Bb[bbase];
                b[1] = *(const bf16x8*)&Bb[bbase + 512];
#pragma unroll
                for (int mf = 0; mf < 2; ++mf)
#pragma unroll
                    for (int nf = 0; nf < 2; ++nf)
                        acc[mf][nf] = __builtin_amdgcn_mfma_f32_16x16x32_bf16(
                            a[mf], b[nf], acc[mf][nf], 0, 0, 0);
            }
        }
    }
#undef LOADF

    // epilogue: D col = lane&15, row = (lane>>4)*4 + r  (m89-verified layout)
#pragma unroll
    for (int nf = 0; nf < 2; ++nf) {
        int n = nb * 64 + wc * 32 + nf * 16 + (lane & 15);
        const bool isE1 = (n < 512);
        float* dst = isE1 ? E1 : E2;
        int o = n & 511;
        float bias = isE1 ? attn_b[o] : 0.0f;
#pragma unroll
        for (int mf = 0; mf < 2; ++mf) {
            int ml = mb * 128 + wr * 32 + mf * 16 + ((lane >> 4) << 2);
            int bb = ml >> 8, l = ml & 255;
            long rowoff = ((long)(bb * 8 + (l >> 5)) * 512 + o) * 32 + (l & 31);
#pragma unroll
            for (int r = 0; r < 4; ++r)
                dst[rowoff + r] = fast_exp2(SCALE * (acc[mf][nf][r] + bias));
        }
    }
}

// ---------------- stage 2: partial energies v4 (R17) ----------------
// EP[s][b][i][j] = sum_{o in chunk s (128)} c_o * rcp(1 + E1[b,i,o]*E2[b,j,o])
// 64i x 64j tile, 4x4/thread, [o][i] LDS (32-o chunks), 4-way exact rcp combine.
__global__ __launch_bounds__(256) void energy_kernel(const float* __restrict__ E1,
                                                     const float* __restrict__ E2,
                                                     const float* __restrict__ sW,
                                                     float* __restrict__ EP) {
    const int bid = blockIdx.x;       // 512 = s(4) b(8) ti(4) tj(4)
    const int tj = bid & 3;
    const int ti = (bid >> 2) & 3;
    const int b  = (bid >> 4) & 7;
    const int s  = bid >> 7;
    __shared__ float As[32 * 64];
    __shared__ float Bs[32 * 64];
    __shared__ float csh[128];

    const int t = threadIdx.x;
    const int tx = t & 15, ty = t >> 4;

    if (t < 128) csh[t] = 2.0f * sW[s * 128 + t];

    const float* e1base = E1 + (long)(b * 8 + ti * 2) * 16384;
    const float* e2base = E2 + (long)(b * 8 + tj * 2) * 16384;

    float acc[4][4];
#pragma unroll
    for (int i = 0; i < 4; ++i)
#pragma unroll
        for (int j = 0; j < 4; ++j) acc[i][j] = 0.f;

    for (int c0 = 0; c0 < 128; c0 += 32) {
        __syncthreads();
#pragma unroll
        for (int it = 0; it < 2; ++it) {
            const int f = it * 256 + t;
            const int ol = f >> 4;
            const int i4 = (f & 15) * 4;
            const long srcoff = (long)(i4 >> 5) * 16384 + (long)(s * 128 + c0 + ol) * 32 + (i4 & 31);
            *(float4*)&As[ol * 64 + i4] = *(const float4*)(e1base + srcoff);
            *(float4*)&Bs[ol * 64 + i4] = *(const float4*)(e2base + srcoff);
        }
        __syncthreads();

#pragma unroll 2
        for (int p = 0; p < 8; ++p) {
            const float4 c4 = *(const float4*)&csh[c0 + p * 4];
            float4 a0 = *(const float4*)&As[(p * 4 + 0) * 64 + ty * 4];
            float4 a1 = *(const float4*)&As[(p * 4 + 1) * 64 + ty * 4];
            float4 a2 = *(const float4*)&As[(p * 4 + 2) * 64 + ty * 4];
            float4 a3 = *(const float4*)&As[(p * 4 + 3) * 64 + ty * 4];
            float4 b0 = *(const float4*)&Bs[(p * 4 + 0) * 64 + tx * 4];
            float4 b1 = *(const float4*)&Bs[(p * 4 + 1) * 64 + tx * 4];
            float4 b2 = *(const float4*)&Bs[(p * 4 + 2) * 64 + tx * 4];
            float4 b3 = *(const float4*)&Bs[(p * 4 + 3) * 64 + tx * 4];
            const float a0v[4] = {a0.x, a0.y, a0.z, a0.w};
            const float a1v[4] = {a1.x, a1.y, a1.z, a1.w};
            const float a2v[4] = {a2.x, a2.y, a2.z, a2.w};
            const float a3v[4] = {a3.x, a3.y, a3.z, a3.w};
            const float b0v[4] = {b0.x, b0.y, b0.z, b0.w};
            const float b1v[4] = {b1.x, b1.y, b1.z, b1.w};
            const float b2v[4] = {b2.x, b2.y, b2.z, b2.w};
            const float b3v[4] = {b3.x, b3.y, b3.z, b3.w};
#pragma unroll
            for (int i = 0; i < 4; ++i) {
#pragma unroll
                for (int j = 0; j < 4; ++j) {
                    float y0 = fmaf(a0v[i], b0v[j], 1.0f);
                    float y1 = fmaf(a1v[i], b1v[j], 1.0f);
                    float y2 = fmaf(a2v[i], b2v[j], 1.0f);
                    float y3 = fmaf(a3v[i], b3v[j], 1.0f);
                    float y01 = y0 * y1, y23 = y2 * y3;
                    float d = y01 * y23;
                    float n01 = fmaf(c4.x, y1, c4.y * y0);
                    float n23 = fmaf(c4.z, y3, c4.w * y2);
                    float n = fmaf(n01, y23, n23 * y01);
                    acc[i][j] = fmaf(n, fast_rcp(d), acc[i][j]);
                }
            }
        }
    }

    float* Eb = EP + (long)s * 524288 + (long)b * 65536 +
                (long)(ti * 64 + ty * 4) * 256 + tj * 64 + tx * 4;
#pragma unroll
    for (int i = 0; i < 4; ++i)
        *(float4*)&Eb[i * 256] = make_float4(acc[i][0], acc[i][1], acc[i][2], acc[i][3]);
}

// ---------------- stage 3: combine partials + softmax over i (axis=1) ----------------
__global__ __launch_bounds__(256) void softmax_kernel(const float* __restrict__ P0,
                                                      const float* __restrict__ P1,
                                                      const float* __restrict__ P2,
                                                      const float* __restrict__ P3,
                                                      float* __restrict__ out) {
    const int b  = blockIdx.x >> 4;
    const int jt = blockIdx.x & 15;
    const int t  = threadIdx.x;
    const int jx = t & 15;
    const int iy = t >> 4;
    const long base = (long)b * 65536 + jt * 16 + jx;

    float v[16];
#pragma unroll
    for (int k = 0; k < 16; ++k) {
        long idx = base + (long)(iy + k * 16) * 256;
        v[k] = -(P0[idx] + P1[idx] + P2[idx] + P3[idx]);
    }

    float m = v[0];
#pragma unroll
    for (int k = 1; k < 16; ++k) m = fmaxf(m, v[k]);

    __shared__ float red[256];
    red[t] = m;
    __syncthreads();
    if (t < 128) red[t] = fmaxf(red[t], red[t + 128]);
    __syncthreads();
    if (t < 64) red[t] = fmaxf(red[t], red[t + 64]);
    __syncthreads();
    if (t < 32) red[t] = fmaxf(red[t], red[t + 32]);
    __syncthreads();
    if (t < 16) red[t] = fmaxf(red[t], red[t + 16]);
    __syncthreads();
    m = red[jx];
    __syncthreads();

    float ssum = 0.f;
#pragma unroll
    for (int k = 0; k < 16; ++k) {
        v[k] = fast_exp2((v[k] - m) * LOG2E);
        ssum += v[k];
    }
    red[t] = ssum;
    __syncthreads();
    if (t < 128) red[t] += red[t + 128];
    __syncthreads();
    if (t < 64) red[t] += red[t + 64];
    __syncthreads();
    if (t < 32) red[t] += red[t + 32];
    __syncthreads();
    if (t < 16) red[t] += red[t + 16];
    __syncthreads();
    float inv = fast_rcp(red[jx]);

#pragma unroll
    for (int k = 0; k < 16; ++k) {
        long idx = base + (long)(iy + k * 16) * 256;
        out[idx] = v[k] * inv;
    }
}

extern "C" void kernel_launch(void* const* d_in, const int* in_sizes, int n_in,
                              void* d_out, int out_size, void* d_ws, size_t ws_size,
                              hipStream_t stream) {
    const float* inputs  = (const float*)d_in[0];  // (256, 8, 512)
    const float* attn_W  = (const float*)d_in[1];  // (512, 1024)
    const float* attn_b  = (const float*)d_in[2];  // (512,)
    const float* score_W = (const float*)d_in[3];  // (1, 512)
    float* out = (float*)d_out;                    // (8, 256, 256)

    float* ws = (float*)d_ws;
    float* E1 = ws;                                // 1M f32 exp panel
    float* E2 = ws + (1 << 20);                    // 1M f32
    float* EP = ws + (2 << 20);                    // 4 * 512K f32 partials (8 MB)

    mfma_gemm<<<256, 512, 0, stream>>>(inputs, attn_W, attn_b, E1, E2);
    energy_kernel<<<512, 256, 0, stream>>>(E1, E2, score_W, EP);
    softmax_kernel<<<128, 256, 0, stream>>>(EP, EP + 524288, EP + 2 * 524288,
                                            EP + 3 * 524288, out);
}